// Round 5
// baseline (145.320 us; speedup 1.0000x reference)
//
#include <hip/hip_runtime.h>

// GWD loss: pred(N,5) f32, target(N,5) f32, weight(N) f32 -> scalar mean.
// Round 5: max occupancy. 512-row chunks, 2 rows/thread, float2 staging
// (5 independent loads/array, 8 lines per 512 useful bytes), 20.5 KB LDS
// -> 8 blocks/CU x 4 waves = 32 waves/CU (HW max), low VGPR (<64).
// FUN='log', TAU=1.0, ALPHA=1.0, LOSS_WEIGHT=1.0.

#define CHUNK_ROWS 512   // 512 rows * 5 floats = 2560 = 1280 float2 = 5/thread

__device__ __forceinline__ float gwd_row(const float* __restrict__ p,
                                         const float* __restrict__ t)
{
    const float px = p[0], py = p[1], pw = p[2], ph = p[3], pr = p[4];
    const float tx = t[0], ty = t[1], tw = t[2], th = t[3], tr = t[4];

    const float dx = px - tx;
    const float dy = py - ty;
    const float xy_dist = dx * dx + dy * dy;

    const float a2p = 0.25f * pw * pw;
    const float b2p = 0.25f * ph * ph;
    const float a2t = 0.25f * tw * tw;
    const float b2t = 0.25f * th * th;

    float whr = (a2p + b2p) + (a2t + b2t);

    float cp, sp, ct, st;
    __sincosf(pr, &sp, &cp);
    __sincosf(tr, &st, &ct);

    // Sigma = R diag(a2,b2) R^T
    const float Sp00 = cp * cp * a2p + sp * sp * b2p;
    const float Sp01 = cp * sp * (a2p - b2p);
    const float Sp11 = sp * sp * a2p + cp * cp * b2p;
    const float St00 = ct * ct * a2t + st * st * b2t;
    const float St01 = ct * st * (a2t - b2t);
    const float St11 = st * st * a2t + ct * ct * b2t;

    // tr(Sp^1/2 St Sp^1/2) = tr(Sp St); det(cross) = det(Sp)det(St) >= 0
    const float tr_cross  = Sp00 * St00 + 2.0f * Sp01 * St01 + Sp11 * St11;
    const float det_cross = (a2p * b2p) * (a2t * b2t);

    float sq = fmaxf(tr_cross + 2.0f * sqrtf(det_cross), 0.0f);
    whr = whr - 2.0f * sqrtf(sq);

    float distance = sqrtf(fmaxf(xy_dist + whr, 0.0f));   // ALPHA = 1

    const float prod = (pw * tw) * (ph * th);
    distance = distance / sqrtf(sqrtf(prod));             // (prod)^(-1/4)

    distance = log1pf(distance);                          // FUN = 'log'
    return 1.0f - 1.0f / (1.0f + distance);               // TAU = 1
}

__global__ __launch_bounds__(256, 8) void gwd_loss_kernel(
    const float* __restrict__ pred,
    const float* __restrict__ target,
    const float* __restrict__ weight,
    float* __restrict__ out,
    int n)
{
    // 2 x 10240 B = 20480 B LDS -> exactly 8 blocks/CU (163840/20480)
    __shared__ float s_pred[CHUNK_ROWS * 5];
    __shared__ float s_tgt [CHUNK_ROWS * 5];

    const float inv_n = 1.0f / (float)n;
    const int row0 = blockIdx.x * CHUNK_ROWS;
    const int tid  = threadIdx.x;
    float acc = 0.0f;

    if (row0 + CHUNK_ROWS <= n) {
        // ---- full chunk: coalesced float2 staging, all loads in flight ----
        const float2* p2 = (const float2*)(pred   + (size_t)row0 * 5);
        const float2* t2 = (const float2*)(target + (size_t)row0 * 5);

        float2 P[5], T[5];
        #pragma unroll
        for (int j = 0; j < 5; ++j) P[j] = p2[j * 256 + tid];
        #pragma unroll
        for (int j = 0; j < 5; ++j) T[j] = t2[j * 256 + tid];
        const float w0 = weight[row0 + tid];
        const float w1 = weight[row0 + 256 + tid];

        #pragma unroll
        for (int j = 0; j < 5; ++j) ((float2*)s_pred)[j * 256 + tid] = P[j];
        #pragma unroll
        for (int j = 0; j < 5; ++j) ((float2*)s_tgt )[j * 256 + tid] = T[j];
        __syncthreads();

        // ---- compute: rows tid, tid+256 (LDS dword-stride 5: gcd(5,32)=1, free) ----
        acc  = gwd_row(&s_pred[tid * 5],          &s_tgt[tid * 5])          * w0;
        acc += gwd_row(&s_pred[(tid + 256) * 5],  &s_tgt[(tid + 256) * 5])  * w1;
    } else {
        // ---- tail block (at most one): direct scalar path ----
        for (int r = row0 + tid; r < n; r += 256) {
            float pb[5], tb[5];
            #pragma unroll
            for (int k = 0; k < 5; ++k) {
                pb[k] = pred  [(size_t)r * 5 + k];
                tb[k] = target[(size_t)r * 5 + k];
            }
            acc += gwd_row(pb, tb) * weight[r];
        }
    }

    // ---- wave-64 -> block -> global reduction (reuse s_pred as scratch) ----
    #pragma unroll
    for (int off = 32; off > 0; off >>= 1)
        acc += __shfl_down(acc, off, 64);

    __syncthreads();   // all LDS compute reads done before reuse
    const int lane = tid & 63;
    const int wid  = tid >> 6;
    if (lane == 0) s_pred[wid] = acc;
    __syncthreads();

    if (tid == 0) {
        const float s = (s_pred[0] + s_pred[1]) + (s_pred[2] + s_pred[3]);
        atomicAdd(out, s * inv_n);   // LOSS_WEIGHT = 1
    }
}

extern "C" void kernel_launch(void* const* d_in, const int* in_sizes, int n_in,
                              void* d_out, int out_size, void* d_ws, size_t ws_size,
                              hipStream_t stream) {
    const float* pred   = (const float*)d_in[0];
    const float* target = (const float*)d_in[1];
    const float* weight = (const float*)d_in[2];
    float* out = (float*)d_out;

    const int n = in_sizes[2];   // weight has N elements

    // harness poisons d_out with 0xAA before every timed launch
    hipMemsetAsync(out, 0, sizeof(float), stream);

    const int block = 256;
    const int grid  = (n + CHUNK_ROWS - 1) / CHUNK_ROWS;   // 3907 for N=2e6
    gwd_loss_kernel<<<grid, block, 0, stream>>>(pred, target, weight, out, n);
}

// Round 6
// 106.459 us; speedup vs baseline: 1.3650x; 1.3650x over previous
//
#include <hip/hip_runtime.h>

// GWD loss: pred(N,5) f32, target(N,5) f32, weight(N) f32 -> scalar mean.
// Round 6: block-count is the first-order cost (~8.6 ns/block measured across
// R1/R3/R4/R5). Structure: 1024 blocks, no LDS staging, float4-AoS loads
// (4 rows/thread/group, ~2 groups/thread grid-stride), per-block partials to
// d_ws (no atomics), tiny kernel2 reduces + writes out (replaces memset).
// Fast transcendentals: v_sqrt/v_rcp/v_rsq/v_log raw (threshold 4.7e-3).
// FUN='log', TAU=1.0, ALPHA=1.0, LOSS_WEIGHT=1.0.

#define NBLK 1024

__device__ __forceinline__ float gwd_row(const float* __restrict__ p,
                                         const float* __restrict__ t)
{
    const float px = p[0], py = p[1], pw = p[2], ph = p[3], pr = p[4];
    const float tx = t[0], ty = t[1], tw = t[2], th = t[3], tr = t[4];

    const float dx = px - tx;
    const float dy = py - ty;
    const float xy_dist = dx * dx + dy * dy;

    const float a2p = 0.25f * pw * pw;
    const float b2p = 0.25f * ph * ph;
    const float a2t = 0.25f * tw * tw;
    const float b2t = 0.25f * th * th;

    float whr = (a2p + b2p) + (a2t + b2t);

    float cp, sp, ct, st;
    __sincosf(pr, &sp, &cp);
    __sincosf(tr, &st, &ct);

    // Sigma = R diag(a2,b2) R^T
    const float Sp00 = cp * cp * a2p + sp * sp * b2p;
    const float Sp01 = cp * sp * (a2p - b2p);
    const float Sp11 = sp * sp * a2p + cp * cp * b2p;
    const float St00 = ct * ct * a2t + st * st * b2t;
    const float St01 = ct * st * (a2t - b2t);
    const float St11 = st * st * a2t + ct * ct * b2t;

    // tr(Sp^1/2 St Sp^1/2) = tr(Sp St); det(cross) = det(Sp)det(St) >= 0
    const float tr_cross  = Sp00 * St00 + 2.0f * Sp01 * St01 + Sp11 * St11;
    const float det_cross = (a2p * b2p) * (a2t * b2t);

    const float sq = fmaxf(tr_cross + 2.0f * __builtin_amdgcn_sqrtf(det_cross), 0.0f);
    whr = whr - 2.0f * __builtin_amdgcn_sqrtf(sq);

    float d = __builtin_amdgcn_sqrtf(fmaxf(xy_dist + whr, 0.0f));   // ALPHA = 1

    // d /= prod^(1/4)  ==  d *= rsq(sqrt(prod))
    const float prod = (pw * tw) * (ph * th);
    d *= __builtin_amdgcn_rsqf(__builtin_amdgcn_sqrtf(prod));

    // FUN='log': log1p(d) = ln(1+d) = log2(1+d) * ln2  (d >= 0, no cancellation)
    d = 0.69314718056f * __builtin_amdgcn_logf(1.0f + d);

    // TAU=1: 1 - 1/(1+d)
    return 1.0f - __builtin_amdgcn_rcpf(1.0f + d);
}

__global__ __launch_bounds__(256) void gwd_partial(
    const float* __restrict__ pred,
    const float* __restrict__ target,
    const float* __restrict__ weight,
    float* __restrict__ ws,
    int n)
{
    const int tid = threadIdx.x;
    const int ngroups = n >> 2;                 // full groups of 4 rows
    float acc = 0.0f;

    for (int g = blockIdx.x * 256 + tid; g < ngroups; g += NBLK * 256) {
        const float4* p4 = (const float4*)pred   + (size_t)g * 5;
        const float4* t4 = (const float4*)target + (size_t)g * 5;

        float4 P[5], T[5];
        #pragma unroll
        for (int j = 0; j < 5; ++j) P[j] = p4[j];
        #pragma unroll
        for (int j = 0; j < 5; ++j) T[j] = t4[j];
        const float4 w4 = ((const float4*)weight)[g];

        float pbuf[20], tbuf[20];
        #pragma unroll
        for (int j = 0; j < 5; ++j) { *(float4*)(pbuf + 4 * j) = P[j];
                                      *(float4*)(tbuf + 4 * j) = T[j]; }
        const float w[4] = { w4.x, w4.y, w4.z, w4.w };
        #pragma unroll
        for (int j = 0; j < 4; ++j)
            acc += gwd_row(&pbuf[j * 5], &tbuf[j * 5]) * w[j];
    }

    // wave-64 -> block reduction, one plain store per block (no atomics)
    #pragma unroll
    for (int off = 32; off > 0; off >>= 1)
        acc += __shfl_down(acc, off, 64);

    __shared__ float wave_sums[4];
    const int lane = tid & 63;
    const int wid  = tid >> 6;
    if (lane == 0) wave_sums[wid] = acc;
    __syncthreads();

    if (tid == 0)
        ws[blockIdx.x] = (wave_sums[0] + wave_sums[1]) + (wave_sums[2] + wave_sums[3]);
}

__global__ __launch_bounds__(256) void gwd_final(
    const float* __restrict__ ws,
    const float* __restrict__ pred,
    const float* __restrict__ target,
    const float* __restrict__ weight,
    float* __restrict__ out,
    int n)
{
    const int tid = threadIdx.x;
    float acc = 0.0f;

    #pragma unroll
    for (int j = 0; j < NBLK / 256; ++j)
        acc += ws[j * 256 + tid];

    // tail rows (n % 4), handled scalar by the first few threads
    const int tail0 = n & ~3;
    if (tid < (n - tail0)) {
        const int r = tail0 + tid;
        float pb[5], tb[5];
        #pragma unroll
        for (int k = 0; k < 5; ++k) {
            pb[k] = pred  [(size_t)r * 5 + k];
            tb[k] = target[(size_t)r * 5 + k];
        }
        acc += gwd_row(pb, tb) * weight[r];
    }

    #pragma unroll
    for (int off = 32; off > 0; off >>= 1)
        acc += __shfl_down(acc, off, 64);

    __shared__ float wave_sums[4];
    const int lane = tid & 63;
    const int wid  = tid >> 6;
    if (lane == 0) wave_sums[wid] = acc;
    __syncthreads();

    if (tid == 0) {
        const float s = (wave_sums[0] + wave_sums[1]) + (wave_sums[2] + wave_sums[3]);
        out[0] = s * (1.0f / (float)n);   // LOSS_WEIGHT = 1; overwrites poison
    }
}

extern "C" void kernel_launch(void* const* d_in, const int* in_sizes, int n_in,
                              void* d_out, int out_size, void* d_ws, size_t ws_size,
                              hipStream_t stream) {
    const float* pred   = (const float*)d_in[0];
    const float* target = (const float*)d_in[1];
    const float* weight = (const float*)d_in[2];
    float* out = (float*)d_out;
    float* ws  = (float*)d_ws;   // NBLK floats of partials (written every call)

    const int n = in_sizes[2];   // weight has N elements

    gwd_partial<<<NBLK, 256, 0, stream>>>(pred, target, weight, ws, n);
    gwd_final<<<1, 256, 0, stream>>>(ws, pred, target, weight, out, n);
}